// Round 11
// baseline (706.517 us; speedup 1.0000x reference)
//
#include <hip/hip_runtime.h>
#include <hip/hip_bf16.h>

#define F_IN   74
#define KPAD   96
#define HDIM   256
#define NHEAD  8
#define HEADD  32
#define NLAYER 4
#define SLOPE  0.2f
#define EPSN   1e-5f
#define LOG2E  1.44269504088896f

typedef __attribute__((ext_vector_type(8))) short bf16x8;
typedef __attribute__((ext_vector_type(4))) float f32x4;
typedef __attribute__((ext_vector_type(2))) float f32x2;

__device__ __forceinline__ float bf2f(unsigned short u){
  union { unsigned int i; float f; } x; x.i = ((unsigned int)u) << 16; return x.f;
}
__device__ __forceinline__ unsigned short f2bf(float f){
  union { float f; unsigned int i; } x; x.f = f;
  unsigned int u = x.i;
  return (unsigned short)((u + 0x7FFFu + ((u >> 16) & 1u)) >> 16);
}
__device__ __forceinline__ f32x2 bfpair(unsigned int u){
  union { unsigned int i; float f; } lo, hi;
  lo.i = u << 16; hi.i = u & 0xffff0000u;
  return (f32x2){lo.f, hi.f};
}
__device__ __forceinline__ float hw_exp2(float p){
  float r;
  asm volatile("v_exp_f32 %0, %1" : "=v"(r) : "v"(p));
  return r;
}
// 8-lane-group sum via DPP (full-rate VALU, no LDS pipe)
__device__ __forceinline__ float dpp_sum8(float p){
  int t;
  t = __builtin_amdgcn_update_dpp(0, __float_as_int(p), 0xB1, 0xF, 0xF, true);  // quad xor1
  p += __int_as_float(t);
  t = __builtin_amdgcn_update_dpp(0, __float_as_int(p), 0x4E, 0xF, 0xF, true);  // quad xor2
  p += __int_as_float(t);
  t = __builtin_amdgcn_update_dpp(0, __float_as_int(p), 0x141, 0xF, 0xF, true); // half-mirror
  p += __int_as_float(t);
  return p;
}
// 16-lane-group sum via DPP
__device__ __forceinline__ float dpp_sum16(float p){
  int t;
  p = dpp_sum8(p);
  t = __builtin_amdgcn_update_dpp(0, __float_as_int(p), 0x140, 0xF, 0xF, true); // row mirror
  p += __int_as_float(t);
  return p;
}

// ---------------- CSR build (dst-grouped) ----------------
__global__ void k_hist(const int* __restrict__ dst, int* __restrict__ deg, int e){
  int i = blockIdx.x * 256 + threadIdx.x;
  if (i < e) atomicAdd(&deg[dst[i]], 1);
}

__global__ __launch_bounds__(256) void k_scan1(const int* __restrict__ deg,
    int* __restrict__ rowp, int* __restrict__ bsum, int n){
  __shared__ int wsum[4];
  const int tid = threadIdx.x, lane = tid & 63, wid = tid >> 6;
  const int i = blockIdx.x * 256 + tid;
  int v = (i < n) ? (deg[i] + 1) : 0;   // +1 self-loop
  int xv = v;
  #pragma unroll
  for (int off = 1; off < 64; off <<= 1){
    int t = __shfl_up(xv, off);
    if (lane >= off) xv += t;
  }
  if (lane == 63) wsum[wid] = xv;
  __syncthreads();
  int woff = 0, total = 0;
  #pragma unroll
  for (int w = 0; w < 4; ++w){
    int s = wsum[w];
    total += s;
    if (w < wid) woff += s;
  }
  if (i < n) rowp[i] = woff + xv - v;    // local exclusive
  if (tid == 0) bsum[blockIdx.x] = total;
}
__global__ __launch_bounds__(256) void k_scan2(const int* __restrict__ bsum,
    int* __restrict__ boff, int nb){
  __shared__ int wsum[4];
  const int tid = threadIdx.x, lane = tid & 63, wid = tid >> 6;
  int v = (tid < nb) ? bsum[tid] : 0;
  int xv = v;
  #pragma unroll
  for (int off = 1; off < 64; off <<= 1){
    int t = __shfl_up(xv, off);
    if (lane >= off) xv += t;
  }
  if (lane == 63) wsum[wid] = xv;
  __syncthreads();
  int woff = 0, total = 0;
  #pragma unroll
  for (int w = 0; w < 4; ++w){
    int s = wsum[w];
    total += s;
    if (w < wid) woff += s;
  }
  if (tid <= nb) boff[tid] = woff + xv - v;
  if (tid == 0) boff[nb] = total;
}
__global__ void k_scan3(int* __restrict__ rowp, int* __restrict__ cur,
                        const int* __restrict__ boff, int n, int nb){
  int i = blockIdx.x * 256 + threadIdx.x;
  if (i < n){
    int v = rowp[i] + boff[blockIdx.x];
    rowp[i] = v;
    cur[i] = v;
  }
  if (i == 0) rowp[n] = boff[nb];
}

// edges then self-loops in one launch; csr stores BYTE offsets (src*1024)
__global__ void k_fill2(const int* __restrict__ src, const int* __restrict__ dst,
                        int* __restrict__ cur, unsigned int* __restrict__ csr,
                        int e, int n){
  int i = blockIdx.x * 256 + threadIdx.x;
  if (i < e){
    int p = atomicAdd(&cur[dst[i]], 1);
    csr[p] = ((unsigned int)src[i]) << 10;
  } else if (i < e + n){
    int v = i - e;
    int p = atomicAdd(&cur[v], 1);
    csr[p] = ((unsigned int)v) << 10;
  }
}

// ---------------- fused prep ----------------
// GEMM B matrices in MFMA-fragment-major layout (K=256 -> 8 k-slices):
//   fragaddr(col,k) = ((col/16 * 8 + k/32) * 64 + ((col&15) | ((k>>3)&3)<<4)) * 8 + (k&7)
__global__ __launch_bounds__(256) void k_prep(
    const float* __restrict__ wl, const float* __restrict__ wr,
    const float* __restrict__ out_w, const float* __restrict__ in_w,
    const float* __restrict__ wl_b, const float* __restrict__ wr_b,
    const float* __restrict__ x,
    unsigned short* __restrict__ WtLR, unsigned short* __restrict__ WtO,
    unsigned short* __restrict__ WtI, float* __restrict__ bconc,
    unsigned short* __restrict__ xb, int n)
{
  const int b = blockIdx.x;
  const int tid = threadIdx.x;
  if (b < 576){
    __shared__ float tile[32][33];
    const float* Wm;
    unsigned short* Wo;
    int rem, colbase;
    if (b < 512){
      const int matset = b >> 8;        // 0=wl, 1=wr
      const int mat = (b >> 6) & 3;
      rem = b & 63;
      const float* srcw = matset ? wr : wl;
      Wm = srcw + (size_t)mat * HDIM * HDIM;
      Wo = WtLR + (size_t)mat * 512 * HDIM;
      colbase = matset * 256;
    } else {
      rem = b - 512;
      Wm = out_w; Wo = WtO; colbase = 0;
    }
    const int c0 = (rem & 7) * 32, r0 = (rem >> 3) * 32;
    const int tx = tid & 31, ty = tid >> 5;
    #pragma unroll
    for (int i = 0; i < 32; i += 8)
      tile[ty + i][tx] = Wm[(size_t)(r0 + ty + i) * HDIM + c0 + tx];
    __syncthreads();
    #pragma unroll
    for (int i = 0; i < 32; i += 8){
      const int col = colbase + c0 + ty + i;     // N dim
      const int k   = r0 + tx;                   // K dim
      const int cb = col >> 4, ks = k >> 5;
      const int lf = (col & 15) | (((k >> 3) & 3) << 4);
      Wo[((size_t)(cb * 8 + ks) * 64 + lf) * 8 + (k & 7)] = f2bf(tile[tx][ty + i]);
    }
  } else if (b < 672){
    int idx = (b - 576) * 256 + tid;          // < 256*96
    int c = idx / KPAD, k = idx - c * KPAD;
    float v = (k < F_IN) ? in_w[(size_t)k * HDIM + c] : 0.f;
    WtI[idx] = f2bf(v);
  } else if (b < 680){
    int i = (b - 672) * 256 + tid;
    if (i < NLAYER * 512){
      int layer = i >> 9, c = i & 511;
      bconc[i] = (c < 256) ? wl_b[layer * 256 + c] : wr_b[layer * 256 + (c - 256)];
    }
  } else {
    int idx = (b - 680) * 256 + tid;
    if (idx < n * KPAD){
      int row = idx / KPAD, k = idx - row * KPAD;
      float v = (k < F_IN) ? x[(size_t)row * F_IN + k] : 0.f;
      xb[idx] = f2bf(v);
    }
  }
}

// ---------------- input projection via MFMA, K=96, no LDS ----------------
__global__ __launch_bounds__(256) void k_inproj_mfma(
    const unsigned short* __restrict__ xb, const unsigned short* __restrict__ Wt,
    const float* __restrict__ bias, unsigned short* __restrict__ C, int M)
{
  const int l = threadIdx.x & 63;
  const int w = threadIdx.x >> 6;
  const int wm = w >> 1, wn = w & 1;
  const int row0 = blockIdx.x * 128;
  const int col0 = blockIdx.y * 128;

  f32x4 acc[4][4];
  #pragma unroll
  for (int i = 0; i < 4; ++i)
    #pragma unroll
    for (int j = 0; j < 4; ++j) acc[i][j] = (f32x4){0.f, 0.f, 0.f, 0.f};

  #pragma unroll
  for (int kk = 0; kk < 3; ++kk){
    const int kof = kk * 32 + (l >> 4) * 8;
    bf16x8 af[4], bfr[4];
    #pragma unroll
    for (int mi = 0; mi < 4; ++mi){
      int row = row0 + wm * 64 + mi * 16 + (l & 15);
      if (row > M - 1) row = M - 1;
      af[mi] = *(const bf16x8*)(xb + (size_t)row * KPAD + kof);
    }
    #pragma unroll
    for (int ni = 0; ni < 4; ++ni){
      const int col = col0 + wn * 64 + ni * 16 + (l & 15);
      bfr[ni] = *(const bf16x8*)(Wt + (size_t)col * KPAD + kof);
    }
    #pragma unroll
    for (int mi = 0; mi < 4; ++mi)
      #pragma unroll
      for (int ni = 0; ni < 4; ++ni)
        acc[mi][ni] = __builtin_amdgcn_mfma_f32_16x16x32_bf16(
            af[mi], bfr[ni], acc[mi][ni], 0, 0, 0);
  }

  #pragma unroll
  for (int mi = 0; mi < 4; ++mi){
    #pragma unroll
    for (int ni = 0; ni < 4; ++ni){
      const int col = col0 + wn * 64 + ni * 16 + (l & 15);
      const float bv = bias[col];
      #pragma unroll
      for (int r = 0; r < 4; ++r){
        const int row = row0 + wm * 64 + mi * 16 + (l >> 4) * 4 + r;
        if (row < M) C[(size_t)row * HDIM + col] = f2bf(acc[mi][ni][r] + bv);
      }
    }
  }
}

// ---------------- MFMA GEMM: NO LDS, no barriers. A and B both direct from L2.
// A row-major [M][256]; B fragment-major. 128x128 tile, 4 waves (2x2), K=256.
__global__ __launch_bounds__(256) void k_gemm_mfma(
    const unsigned short* __restrict__ A, const unsigned short* __restrict__ Wt,
    const float* __restrict__ bias, unsigned short* __restrict__ C, int M, int ldc)
{
  const int tid = threadIdx.x;
  const int l   = tid & 63;
  const int w   = tid >> 6;
  const int wm  = w >> 1, wn = w & 1;
  const int row0 = blockIdx.x * 128;
  const int col0 = blockIdx.y * 128;

  // per-lane A row pointers (4 sub-tiles), clamped
  const unsigned short* Ap[4];
  #pragma unroll
  for (int mi = 0; mi < 4; ++mi){
    int r = row0 + wm * 64 + mi * 16 + (l & 15);
    if (r > M - 1) r = M - 1;
    Ap[mi] = A + (size_t)r * HDIM + (l >> 4) * 8;
  }
  const unsigned short* Bf = Wt + ((size_t)(col0 / 16 + wn * 4) * 8 * 64 + l) * 8;

  f32x4 acc[4][4];
  #pragma unroll
  for (int i = 0; i < 4; ++i)
    #pragma unroll
    for (int j = 0; j < 4; ++j) acc[i][j] = (f32x4){0.f, 0.f, 0.f, 0.f};

  #pragma unroll
  for (int ks = 0; ks < 8; ++ks){
    bf16x8 af[4], bfr[4];
    #pragma unroll
    for (int mi = 0; mi < 4; ++mi)
      af[mi] = *(const bf16x8*)(Ap[mi] + ks * 32);
    #pragma unroll
    for (int ni = 0; ni < 4; ++ni)
      bfr[ni] = *(const bf16x8*)(Bf + ((size_t)ni * 8 + ks) * 64 * 8);
    #pragma unroll
    for (int mi = 0; mi < 4; ++mi)
      #pragma unroll
      for (int ni = 0; ni < 4; ++ni)
        acc[mi][ni] = __builtin_amdgcn_mfma_f32_16x16x32_bf16(
            af[mi], bfr[ni], acc[mi][ni], 0, 0, 0);
  }

  #pragma unroll
  for (int mi = 0; mi < 4; ++mi){
    #pragma unroll
    for (int ni = 0; ni < 4; ++ni){
      const int col = col0 + wn * 64 + ni * 16 + (l & 15);
      const float bv = bias[col];
      #pragma unroll
      for (int r = 0; r < 4; ++r){
        const int row = row0 + wm * 64 + mi * 16 + (l >> 4) * 4 + r;
        if (row < M) C[(size_t)row * ldc + col] = f2bf(acc[mi][ni][r] + bv);
      }
    }
  }
}

// ---------------- fused GATv2: 4-edge unroll, HW exp2, OR-addressing, DPP reduces, LN + relu ----------------
__global__ __launch_bounds__(256) void k_gat(
    const unsigned short* __restrict__ xlr,
    const int* __restrict__ rp, const unsigned int* __restrict__ csr,
    const float* __restrict__ att, const float* __restrict__ gb,
    const float* __restrict__ lg, const float* __restrict__ lb,
    const unsigned short* __restrict__ hold, unsigned short* __restrict__ hnew,
    int n, int use_res)
{
  const int node = blockIdx.x * 4 + (threadIdx.x >> 6);
  if (node >= n) return;
  const int lane = threadIdx.x & 63;
  const int elem = lane << 2;
  const int head = lane >> 3;
  float4 attv = *(const float4*)(att + head * HEADD + (elem & 31));
  const f32x2 av01 = {attv.x * LOG2E, attv.y * LOG2E};
  const f32x2 av23 = {attv.z * LOG2E, attv.w * LOG2E};
  uint2 ur = *(const uint2*)(xlr + (size_t)node * 512 + 256 + elem);
  const f32x2 r01 = bfpair(ur.x), r23 = bfpair(ur.y);

  const unsigned int ebyte = (unsigned int)(elem << 1);
  const char* xb8 = (const char*)xlr;

  f32x2 a01 = {0.f, 0.f}, a23 = {0.f, 0.f};
  float l = 0.f;

  auto edgeq = [&](uint2 uu, f32x2& x01, f32x2& x23)->float{
    x01 = bfpair(uu.x); x23 = bfpair(uu.y);
    f32x2 t01 = x01 + r01, t23 = x23 + r23;
    f32x2 m01 = __builtin_elementwise_max(t01, t01 * SLOPE);
    f32x2 m23 = __builtin_elementwise_max(t23, t23 * SLOPE);
    f32x2 d = m01 * av01 + m23 * av23;
    float p = dpp_sum8(d.x + d.y);
    return hw_exp2(p);
  };

  const int e0 = rp[node], e1 = rp[node + 1];
  int e = e0;
  for (; e + 4 <= e1; e += 4){
    unsigned int o0 = csr[e] | ebyte, o1 = csr[e + 1] | ebyte;
    unsigned int o2 = csr[e + 2] | ebyte, o3 = csr[e + 3] | ebyte;
    uint2 u0 = *(const uint2*)(xb8 + o0);
    uint2 u1 = *(const uint2*)(xb8 + o1);
    uint2 u2 = *(const uint2*)(xb8 + o2);
    uint2 u3 = *(const uint2*)(xb8 + o3);
    f32x2 x01, x23;
    float q0 = edgeq(u0, x01, x23);
    a01 += q0 * x01; a23 += q0 * x23;
    float q1 = edgeq(u1, x01, x23);
    a01 += q1 * x01; a23 += q1 * x23;
    float q2 = edgeq(u2, x01, x23);
    a01 += q2 * x01; a23 += q2 * x23;
    float q3 = edgeq(u3, x01, x23);
    a01 += q3 * x01; a23 += q3 * x23;
    l += (q0 + q1) + (q2 + q3);
  }
  for (; e < e1; ++e){
    unsigned int o = csr[e] | ebyte;
    uint2 u = *(const uint2*)(xb8 + o);
    f32x2 x01, x23;
    float q = edgeq(u, x01, x23);
    l += q;
    a01 += q * x01; a23 += q * x23;
  }

  const float inv = 1.f / l;
  const size_t base = (size_t)node * HDIM + elem;
  float f0 = a01.x * inv + gb[elem + 0];
  float f1 = a01.y * inv + gb[elem + 1];
  float f2 = a23.x * inv + gb[elem + 2];
  float f3 = a23.y * inv + gb[elem + 3];
  if (use_res){
    ushort4 hv = *(const ushort4*)(hold + base);
    f0 += bf2f(hv.x); f1 += bf2f(hv.y); f2 += bf2f(hv.z); f3 += bf2f(hv.w);
  }
  float s = f0 + f1 + f2 + f3;
  s = dpp_sum16(s);
  s += __shfl_xor(s, 16);
  s += __shfl_xor(s, 32);
  const float mean = s * (1.f / HDIM);
  float d0 = f0 - mean, d1 = f1 - mean, d2 = f2 - mean, d3 = f3 - mean;
  float q = d0 * d0 + d1 * d1 + d2 * d2 + d3 * d3;
  q = dpp_sum16(q);
  q += __shfl_xor(q, 16);
  q += __shfl_xor(q, 32);
  const float rs = rsqrtf(q * (1.f / HDIM) + EPSN);
  float o0 = d0 * rs * lg[elem + 0] + lb[elem + 0]; o0 = o0 > 0.f ? o0 : 0.f;
  float o1 = d1 * rs * lg[elem + 1] + lb[elem + 1]; o1 = o1 > 0.f ? o1 : 0.f;
  float o2 = d2 * rs * lg[elem + 2] + lb[elem + 2]; o2 = o2 > 0.f ? o2 : 0.f;
  float o3 = d3 * rs * lg[elem + 3] + lb[elem + 3]; o3 = o3 > 0.f ? o3 : 0.f;
  ushort4 st; st.x = f2bf(o0); st.y = f2bf(o1); st.z = f2bf(o2); st.w = f2bf(o3);
  *(ushort4*)(hnew + base) = st;
}

// ---------------- mean pool: batch sorted -> per-graph segment reduce ----------------
__global__ __launch_bounds__(256) void k_pool2(
    const unsigned short* __restrict__ ho, const int* __restrict__ batch,
    float* __restrict__ gr, int n)
{
  const int g = blockIdx.x;
  int lo = 0, hi = n;
  while (lo < hi){ int mid = (lo + hi) >> 1; if (batch[mid] < g) lo = mid + 1; else hi = mid; }
  const int s = lo;
  hi = n;
  while (lo < hi){ int mid = (lo + hi) >> 1; if (batch[mid] < g + 1) lo = mid + 1; else hi = mid; }
  const int e = lo;
  const int j = threadIdx.x;
  float acc = 0.f;
  for (int i = s; i < e; ++i) acc += bf2f(ho[(size_t)i * HDIM + j]);
  int c = e - s; if (c < 1) c = 1;
  gr[(size_t)g * HDIM + j] = acc / (float)c;
}

// ---------------- tiny MLP ----------------
__global__ void k_fc(const float* __restrict__ in, const float* __restrict__ w,
                     const float* __restrict__ b, float* __restrict__ out,
                     int kin, int kout){
  __shared__ float s[256];
  int g = blockIdx.x, j = threadIdx.x;
  for (int k = j; k < kin; k += blockDim.x) s[k] = in[(size_t)g * kin + k];
  __syncthreads();
  float a = b[j];
  for (int k = 0; k < kin; ++k) a = fmaf(s[k], w[k * kout + j], a);
  out[(size_t)g * kout + j] = a;
}

// fused BN stats + apply + relu: one block per channel
__global__ __launch_bounds__(256) void k_bn(float* __restrict__ z,
    const float* __restrict__ gam, const float* __restrict__ bet, int g_, int c_){
  const int c = blockIdx.x;
  float s = 0.f, s2 = 0.f;
  for (int r = threadIdx.x; r < g_; r += 256){
    float v = z[(size_t)r * c_ + c];
    s += v; s2 += v * v;
  }
  #pragma unroll
  for (int off = 1; off < 64; off <<= 1){ s += __shfl_xor(s, off); s2 += __shfl_xor(s2, off); }
  __shared__ float sw[4], sw2[4];
  __shared__ float smean, srstd;
  int lane = threadIdx.x & 63, wid = threadIdx.x >> 6;
  if (lane == 0){ sw[wid] = s; sw2[wid] = s2; }
  __syncthreads();
  if (threadIdx.x == 0){
    float ts = sw[0] + sw[1] + sw[2] + sw[3];
    float ts2 = sw2[0] + sw2[1] + sw2[2] + sw2[3];
    float mm = ts / g_;
    float vv = ts2 / g_ - mm * mm;
    smean = mm; srstd = rsqrtf(vv + EPSN);
  }
  __syncthreads();
  const float mm = smean, rs = srstd, gg = gam[c], bb = bet[c];
  for (int r = threadIdx.x; r < g_; r += 256){
    float v = (z[(size_t)r * c_ + c] - mm) * rs * gg + bb;
    z[(size_t)r * c_ + c] = v > 0.f ? v : 0.f;
  }
}

__global__ __launch_bounds__(256) void k_out(const float* __restrict__ z,
    const float* __restrict__ w, const float* __restrict__ b,
    float* __restrict__ out, int g_){
  int g = blockIdx.x * 4 + (threadIdx.x >> 6);
  if (g >= g_) return;
  int lane = threadIdx.x & 63;
  float v = z[(size_t)g * 64 + lane] * w[lane];
  #pragma unroll
  for (int off = 1; off < 64; off <<= 1) v += __shfl_xor(v, off);
  if (lane == 0) out[g] = v + b[0];
}

// ---------------- host ----------------
extern "C" void kernel_launch(void* const* d_in, const int* in_sizes, int n_in,
                              void* d_out, int out_size, void* d_ws, size_t ws_size,
                              hipStream_t stream)
{
  const float* x     = (const float*)d_in[0];
  const int*   ei    = (const int*)  d_in[1];
  const int*   batch = (const int*)  d_in[2];
  const float* in_w  = (const float*)d_in[3];
  const float* in_b  = (const float*)d_in[4];
  const float* wl    = (const float*)d_in[5];
  const float* wl_b  = (const float*)d_in[6];
  const float* wr    = (const float*)d_in[7];
  const float* wr_b  = (const float*)d_in[8];
  const float* att   = (const float*)d_in[9];
  const float* gat_b = (const float*)d_in[10];
  const float* ln_g  = (const float*)d_in[11];
  const float* ln_b  = (const float*)d_in[12];
  const float* out_w = (const float*)d_in[13];
  const float* out_b = (const float*)d_in[14];
  const float* p1_w  = (const float*)d_in[15];
  const float* p1_b  = (const float*)d_in[16];
  const float* bn1_g = (const float*)d_in[17];
  const float* bn1_b = (const float*)d_in[18];
  const float* p2_w  = (const float*)d_in[19];
  const float* p2_b  = (const float*)d_in[20];
  const float* bn2_g = (const float*)d_in[21];
  const float* bn2_b = (const float*)d_in[22];
  const float* p3_w  = (const float*)d_in[23];
  const float* p3_b  = (const float*)d_in[24];

  const int n = in_sizes[0] / F_IN;     // 50000
  const int e = in_sizes[1] / 2;        // 800000
  const int g = out_size;               // 500
  const int nb = (n + 255) / 256;

  char* p = (char*)d_ws;
  auto take = [&](size_t bytes)->char*{
    char* q = p; p += ((bytes + 255) & ~(size_t)255); return q;
  };
  unsigned short* hA   = (unsigned short*)take((size_t)n * HDIM * 2);
  unsigned short* hB   = (unsigned short*)take((size_t)n * HDIM * 2);
  unsigned short* xlr  = (unsigned short*)take((size_t)n * 512 * 2);
  unsigned short* WtLR = (unsigned short*)take((size_t)NLAYER * 512 * HDIM * 2);
  unsigned short* WtO  = (unsigned short*)take((size_t)HDIM * HDIM * 2);
  unsigned short* WtI  = (unsigned short*)take((size_t)HDIM * KPAD * 2);
  float* bconc = (float*)take((size_t)NLAYER * 512 * 4);
  int*   deg   = (int*)take((size_t)n * 4);
  int*   rowp  = (int*)take((size_t)(n + 1) * 4);
  int*   cur   = (int*)take((size_t)n * 4);
  unsigned int* csr = (unsigned int*)take((size_t)(e + n) * 4);
  int*   bsum  = (int*)take((size_t)(nb + 1) * 4);
  int*   boff  = (int*)take((size_t)(nb + 1) * 4);
  float* gr    = (float*)take((size_t)g * HDIM * 4);
  float* z1    = (float*)take((size_t)g * 128 * 4);
  float* z2    = (float*)take((size_t)g * 64 * 4);
  unsigned short* xb = xlr;  // alias: xb only needed before first GEMM writes xlr
  (void)ws_size; (void)n_in;

  // CSR build
  hipMemsetAsync(deg, 0, (size_t)n * 4, stream);
  k_hist<<<(e + 255) / 256, 256, 0, stream>>>(ei + e, deg, e);
  k_scan1<<<nb, 256, 0, stream>>>(deg, rowp, bsum, n);
  k_scan2<<<1, 256, 0, stream>>>(bsum, boff, nb);
  k_scan3<<<nb, 256, 0, stream>>>(rowp, cur, boff, n, nb);
  k_fill2<<<(e + n + 255) / 256, 256, 0, stream>>>(ei, ei + e, cur, csr, e, n);

  // fused prep (weights -> frag layout, biases, x)
  const int xconv_blocks = (n * KPAD + 255) / 256;
  k_prep<<<680 + xconv_blocks, 256, 0, stream>>>(
      wl, wr, out_w, in_w, wl_b, wr_b, x, WtLR, WtO, WtI, bconc, xb, n);

  // input projection (MFMA, K=96)
  k_inproj_mfma<<<dim3((n + 127) / 128, 2), 256, 0, stream>>>(xb, WtI, in_b, hA, n);

  unsigned short* hcur = hA;
  unsigned short* hnext = hB;
  for (int i = 0; i < NLAYER; ++i){
    k_gemm_mfma<<<dim3((n + 127) / 128, 4), 256, 0, stream>>>(
        hcur, WtLR + (size_t)i * 512 * HDIM, bconc + i * 512, xlr, n, 512);
    k_gat<<<(n + 3) / 4, 256, 0, stream>>>(xlr, rowp, csr,
        att + (size_t)i * NHEAD * HEADD, gat_b + i * HDIM,
        ln_g + i * HDIM, ln_b + i * HDIM, hcur, hnext, n, i > 0 ? 1 : 0);
    unsigned short* t = hcur; hcur = hnext; hnext = t;
  }
  // output projection
  k_gemm_mfma<<<dim3((n + 127) / 128, 2), 256, 0, stream>>>(
      hcur, WtO, out_b, hnext, n, HDIM);

  // pooling
  k_pool2<<<g, 256, 0, stream>>>(hnext, batch, gr, n);

  // MLP head
  k_fc<<<g, 128, 0, stream>>>(gr, p1_w, p1_b, z1, HDIM, 128);
  k_bn<<<128, 256, 0, stream>>>(z1, bn1_g, bn1_b, g, 128);
  k_fc<<<g, 64, 0, stream>>>(z1, p2_w, p2_b, z2, 128, 64);
  k_bn<<<64, 256, 0, stream>>>(z2, bn2_g, bn2_b, g, 64);
  k_out<<<(g + 3) / 4, 256, 0, stream>>>(z2, p3_w, p3_b, (float*)d_out, g);
}

// Round 12
// 659.146 us; speedup vs baseline: 1.0719x; 1.0719x over previous
//
#include <hip/hip_runtime.h>
#include <hip/hip_bf16.h>

#define F_IN   74
#define KPAD   96
#define HDIM   256
#define NHEAD  8
#define HEADD  32
#define NLAYER 4
#define SLOPE  0.2f
#define EPSN   1e-5f
#define LOG2E  1.44269504088896f

typedef __attribute__((ext_vector_type(8))) short bf16x8;
typedef __attribute__((ext_vector_type(4))) float f32x4;
typedef __attribute__((ext_vector_type(2))) float f32x2;

__device__ __forceinline__ float bf2f(unsigned short u){
  union { unsigned int i; float f; } x; x.i = ((unsigned int)u) << 16; return x.f;
}
__device__ __forceinline__ unsigned short f2bf(float f){
  union { float f; unsigned int i; } x; x.f = f;
  unsigned int u = x.i;
  return (unsigned short)((u + 0x7FFFu + ((u >> 16) & 1u)) >> 16);
}
__device__ __forceinline__ f32x2 bfpair(unsigned int u){
  union { unsigned int i; float f; } lo, hi;
  lo.i = u << 16; hi.i = u & 0xffff0000u;
  return (f32x2){lo.f, hi.f};
}
__device__ __forceinline__ float hw_exp2(float p){
  float r;
  asm volatile("v_exp_f32 %0, %1" : "=v"(r) : "v"(p));
  return r;
}
// 4-lane (quad) sum via DPP
__device__ __forceinline__ float dpp_sum4(float p){
  int t;
  t = __builtin_amdgcn_update_dpp(0, __float_as_int(p), 0xB1, 0xF, 0xF, true);  // quad xor1
  p += __int_as_float(t);
  t = __builtin_amdgcn_update_dpp(0, __float_as_int(p), 0x4E, 0xF, 0xF, true);  // quad xor2
  p += __int_as_float(t);
  return p;
}
// 16-lane-group sum via DPP
__device__ __forceinline__ float dpp_sum16(float p){
  int t;
  p = dpp_sum4(p);
  t = __builtin_amdgcn_update_dpp(0, __float_as_int(p), 0x141, 0xF, 0xF, true); // half-mirror
  p += __int_as_float(t);
  t = __builtin_amdgcn_update_dpp(0, __float_as_int(p), 0x140, 0xF, 0xF, true); // row mirror
  p += __int_as_float(t);
  return p;
}

#define GLOAD16(g, s) __builtin_amdgcn_global_load_lds( \
  (const __attribute__((address_space(1))) void*)(g), \
  (__attribute__((address_space(3))) void*)(s), 16, 0, 0)

// ---------------- CSR build (dst-grouped) ----------------
__global__ void k_hist(const int* __restrict__ dst, int* __restrict__ deg, int e){
  int i = blockIdx.x * 256 + threadIdx.x;
  if (i < e) atomicAdd(&deg[dst[i]], 1);
}

__global__ __launch_bounds__(256) void k_scan1(const int* __restrict__ deg,
    int* __restrict__ rowp, int* __restrict__ bsum, int n){
  __shared__ int wsum[4];
  const int tid = threadIdx.x, lane = tid & 63, wid = tid >> 6;
  const int i = blockIdx.x * 256 + tid;
  int v = (i < n) ? (deg[i] + 1) : 0;   // +1 self-loop
  int xv = v;
  #pragma unroll
  for (int off = 1; off < 64; off <<= 1){
    int t = __shfl_up(xv, off);
    if (lane >= off) xv += t;
  }
  if (lane == 63) wsum[wid] = xv;
  __syncthreads();
  int woff = 0, total = 0;
  #pragma unroll
  for (int w = 0; w < 4; ++w){
    int s = wsum[w];
    total += s;
    if (w < wid) woff += s;
  }
  if (i < n) rowp[i] = woff + xv - v;    // local exclusive
  if (tid == 0) bsum[blockIdx.x] = total;
}
__global__ __launch_bounds__(256) void k_scan2(const int* __restrict__ bsum,
    int* __restrict__ boff, int nb){
  __shared__ int wsum[4];
  const int tid = threadIdx.x, lane = tid & 63, wid = tid >> 6;
  int v = (tid < nb) ? bsum[tid] : 0;
  int xv = v;
  #pragma unroll
  for (int off = 1; off < 64; off <<= 1){
    int t = __shfl_up(xv, off);
    if (lane >= off) xv += t;
  }
  if (lane == 63) wsum[wid] = xv;
  __syncthreads();
  int woff = 0, total = 0;
  #pragma unroll
  for (int w = 0; w < 4; ++w){
    int s = wsum[w];
    total += s;
    if (w < wid) woff += s;
  }
  if (tid <= nb) boff[tid] = woff + xv - v;
  if (tid == 0) boff[nb] = total;
}
__global__ void k_scan3(int* __restrict__ rowp, int* __restrict__ cur,
                        const int* __restrict__ boff, int n, int nb){
  int i = blockIdx.x * 256 + threadIdx.x;
  if (i < n){
    int v = rowp[i] + boff[blockIdx.x];
    rowp[i] = v;
    cur[i] = v;
  }
  if (i == 0) rowp[n] = boff[nb];
}

// edges then self-loops in one launch; csr stores BYTE offsets (src*1024)
__global__ void k_fill2(const int* __restrict__ src, const int* __restrict__ dst,
                        int* __restrict__ cur, unsigned int* __restrict__ csr,
                        int e, int n){
  int i = blockIdx.x * 256 + threadIdx.x;
  if (i < e){
    int p = atomicAdd(&cur[dst[i]], 1);
    csr[p] = ((unsigned int)src[i]) << 10;
  } else if (i < e + n){
    int v = i - e;
    int p = atomicAdd(&cur[v], 1);
    csr[p] = ((unsigned int)v) << 10;
  }
}

// ---------------- fused prep ----------------
// GEMM B matrices in MFMA-fragment-major layout (K=256 -> 8 k-slices):
//   fragaddr(col,k) = ((col/16 * 8 + k/32) * 64 + ((col&15) | ((k>>3)&3)<<4)) * 8 + (k&7)
__global__ __launch_bounds__(256) void k_prep(
    const float* __restrict__ wl, const float* __restrict__ wr,
    const float* __restrict__ out_w, const float* __restrict__ in_w,
    const float* __restrict__ wl_b, const float* __restrict__ wr_b,
    const float* __restrict__ x,
    unsigned short* __restrict__ WtLR, unsigned short* __restrict__ WtO,
    unsigned short* __restrict__ WtI, float* __restrict__ bconc,
    unsigned short* __restrict__ xb, int n)
{
  const int b = blockIdx.x;
  const int tid = threadIdx.x;
  if (b < 576){
    __shared__ float tile[32][33];
    const float* Wm;
    unsigned short* Wo;
    int rem, colbase;
    if (b < 512){
      const int matset = b >> 8;        // 0=wl, 1=wr
      const int mat = (b >> 6) & 3;
      rem = b & 63;
      const float* srcw = matset ? wr : wl;
      Wm = srcw + (size_t)mat * HDIM * HDIM;
      Wo = WtLR + (size_t)mat * 512 * HDIM;
      colbase = matset * 256;
    } else {
      rem = b - 512;
      Wm = out_w; Wo = WtO; colbase = 0;
    }
    const int c0 = (rem & 7) * 32, r0 = (rem >> 3) * 32;
    const int tx = tid & 31, ty = tid >> 5;
    #pragma unroll
    for (int i = 0; i < 32; i += 8)
      tile[ty + i][tx] = Wm[(size_t)(r0 + ty + i) * HDIM + c0 + tx];
    __syncthreads();
    #pragma unroll
    for (int i = 0; i < 32; i += 8){
      const int col = colbase + c0 + ty + i;     // N dim
      const int k   = r0 + tx;                   // K dim
      const int cb = col >> 4, ks = k >> 5;
      const int lf = (col & 15) | (((k >> 3) & 3) << 4);
      Wo[((size_t)(cb * 8 + ks) * 64 + lf) * 8 + (k & 7)] = f2bf(tile[tx][ty + i]);
    }
  } else if (b < 672){
    int idx = (b - 576) * 256 + tid;          // < 256*96
    int c = idx / KPAD, k = idx - c * KPAD;
    float v = (k < F_IN) ? in_w[(size_t)k * HDIM + c] : 0.f;
    WtI[idx] = f2bf(v);
  } else if (b < 680){
    int i = (b - 672) * 256 + tid;
    if (i < NLAYER * 512){
      int layer = i >> 9, c = i & 511;
      bconc[i] = (c < 256) ? wl_b[layer * 256 + c] : wr_b[layer * 256 + (c - 256)];
    }
  } else {
    int idx = (b - 680) * 256 + tid;
    if (idx < n * KPAD){
      int row = idx / KPAD, k = idx - row * KPAD;
      float v = (k < F_IN) ? x[(size_t)row * F_IN + k] : 0.f;
      xb[idx] = f2bf(v);
    }
  }
}

// ---------------- input projection via MFMA, K=96, no LDS ----------------
__global__ __launch_bounds__(256) void k_inproj_mfma(
    const unsigned short* __restrict__ xb, const unsigned short* __restrict__ Wt,
    const float* __restrict__ bias, unsigned short* __restrict__ C, int M)
{
  const int l = threadIdx.x & 63;
  const int w = threadIdx.x >> 6;
  const int wm = w >> 1, wn = w & 1;
  const int row0 = blockIdx.x * 128;
  const int col0 = blockIdx.y * 128;

  f32x4 acc[4][4];
  #pragma unroll
  for (int i = 0; i < 4; ++i)
    #pragma unroll
    for (int j = 0; j < 4; ++j) acc[i][j] = (f32x4){0.f, 0.f, 0.f, 0.f};

  #pragma unroll
  for (int kk = 0; kk < 3; ++kk){
    const int kof = kk * 32 + (l >> 4) * 8;
    bf16x8 af[4], bfr[4];
    #pragma unroll
    for (int mi = 0; mi < 4; ++mi){
      int row = row0 + wm * 64 + mi * 16 + (l & 15);
      if (row > M - 1) row = M - 1;
      af[mi] = *(const bf16x8*)(xb + (size_t)row * KPAD + kof);
    }
    #pragma unroll
    for (int ni = 0; ni < 4; ++ni){
      const int col = col0 + wn * 64 + ni * 16 + (l & 15);
      bfr[ni] = *(const bf16x8*)(Wt + (size_t)col * KPAD + kof);
    }
    #pragma unroll
    for (int mi = 0; mi < 4; ++mi)
      #pragma unroll
      for (int ni = 0; ni < 4; ++ni)
        acc[mi][ni] = __builtin_amdgcn_mfma_f32_16x16x32_bf16(
            af[mi], bfr[ni], acc[mi][ni], 0, 0, 0);
  }

  #pragma unroll
  for (int mi = 0; mi < 4; ++mi){
    #pragma unroll
    for (int ni = 0; ni < 4; ++ni){
      const int col = col0 + wn * 64 + ni * 16 + (l & 15);
      const float bv = bias[col];
      #pragma unroll
      for (int r = 0; r < 4; ++r){
        const int row = row0 + wm * 64 + mi * 16 + (l >> 4) * 4 + r;
        if (row < M) C[(size_t)row * HDIM + col] = f2bf(acc[mi][ni][r] + bv);
      }
    }
  }
}

// ---------------- MFMA GEMM: A in LDS (dbuf BK=64, swizzled), B direct from L2 frag-major ----------------
__global__ __launch_bounds__(256) void k_gemm_mfma(
    const unsigned short* __restrict__ A, const unsigned short* __restrict__ Wt,
    const float* __restrict__ bias, unsigned short* __restrict__ C, int M, int ldc)
{
  __shared__ unsigned short As[2][128 * 64];
  const int tid = threadIdx.x;
  const int l   = tid & 63;
  const int w   = tid >> 6;
  const int wm  = w >> 1, wn = w & 1;
  const int row0 = blockIdx.x * 128;
  const int col0 = blockIdx.y * 128;

  const int srow   = l >> 3;
  const int schunk = l & 7;

  f32x4 acc[4][4];
  #pragma unroll
  for (int i = 0; i < 4; ++i)
    #pragma unroll
    for (int j = 0; j < 4; ++j) acc[i][j] = (f32x4){0.f, 0.f, 0.f, 0.f};

  auto stageA = [&](int buf, int k0){
    #pragma unroll
    for (int i = 0; i < 4; ++i){
      const int rloc = w * 32 + i * 8 + srow;
      const int sw   = (schunk ^ (rloc & 7)) * 16;
      int ra = row0 + rloc; if (ra > M - 1) ra = M - 1;
      const char* srcA = (const char*)(A + (size_t)ra * HDIM + k0) + sw;
      GLOAD16(srcA, &As[buf][(w * 32 + i * 8) * 64]);
    }
  };

  const unsigned short* Bf = Wt + ((size_t)(col0 / 16 + wn * 4) * 8 * 64 + l) * 8;

  stageA(0, 0);
  asm volatile("s_waitcnt vmcnt(0)" ::: "memory");
  __builtin_amdgcn_s_barrier();
  int buf = 0;
  #pragma unroll
  for (int t = 0; t < 4; ++t){
    bf16x8 bfr[2][4];
    #pragma unroll
    for (int kk = 0; kk < 2; ++kk)
      #pragma unroll
      for (int ni = 0; ni < 4; ++ni)
        bfr[kk][ni] = *(const bf16x8*)(Bf + ((size_t)ni * 8 + (t * 2 + kk)) * 64 * 8);
    if (t < 3) stageA(buf ^ 1, (t + 1) * 64);
    #pragma unroll
    for (int kk = 0; kk < 2; ++kk){
      bf16x8 af[4];
      #pragma unroll
      for (int mi = 0; mi < 4; ++mi){
        const int row = wm * 64 + mi * 16 + (l & 15);
        const int tt  = (kk * 4 + (l >> 4)) ^ (row & 7);
        af[mi] = *(const bf16x8*)((const char*)&As[buf][0] + row * 128 + tt * 16);
      }
      #pragma unroll
      for (int mi = 0; mi < 4; ++mi)
        #pragma unroll
        for (int ni = 0; ni < 4; ++ni)
          acc[mi][ni] = __builtin_amdgcn_mfma_f32_16x16x32_bf16(
              af[mi], bfr[kk][ni], acc[mi][ni], 0, 0, 0);
    }
    if (t < 3){
      asm volatile("s_waitcnt vmcnt(0)" ::: "memory");
      __builtin_amdgcn_s_barrier();
      buf ^= 1;
    }
  }

  #pragma unroll
  for (int mi = 0; mi < 4; ++mi){
    #pragma unroll
    for (int ni = 0; ni < 4; ++ni){
      const int col = col0 + wn * 64 + ni * 16 + (l & 15);
      const float bv = bias[col];
      #pragma unroll
      for (int r = 0; r < 4; ++r){
        const int row = row0 + wm * 64 + mi * 16 + (l >> 4) * 4 + r;
        if (row < M) C[(size_t)row * ldc + col] = f2bf(acc[mi][ni][r] + bv);
      }
    }
  }
}

// ---------------- fused GATv2: 16B/lane, 2 edges per wave-op, quad-DPP score,
// half-split accumulators, coalesced ushort8 output ----------------
__global__ __launch_bounds__(256) void k_gat(
    const unsigned short* __restrict__ xlr,
    const int* __restrict__ rp, const unsigned int* __restrict__ csr,
    const float* __restrict__ att, const float* __restrict__ gb,
    const float* __restrict__ lg, const float* __restrict__ lb,
    const unsigned short* __restrict__ hold, unsigned short* __restrict__ hnew,
    int n, int use_res)
{
  const int node = blockIdx.x * 4 + (threadIdx.x >> 6);
  if (node >= n) return;
  const int lane = threadIdx.x & 63;
  const int sub  = lane & 31;      // channel group: ch = sub*8 .. +7
  const int pair = lane >> 5;      // edge stream 0/1
  const int ch0  = sub << 3;
  const int head = sub >> 2;

  float4 av_lo = *(const float4*)(att + head * HEADD + ((sub & 3) << 3));
  float4 av_hi = *(const float4*)(att + head * HEADD + ((sub & 3) << 3) + 4);
  const f32x2 av0 = {av_lo.x * LOG2E, av_lo.y * LOG2E};
  const f32x2 av1 = {av_lo.z * LOG2E, av_lo.w * LOG2E};
  const f32x2 av2 = {av_hi.x * LOG2E, av_hi.y * LOG2E};
  const f32x2 av3 = {av_hi.z * LOG2E, av_hi.w * LOG2E};

  uint4 ur = *(const uint4*)(xlr + (size_t)node * 512 + 256 + ch0);
  const f32x2 r0 = bfpair(ur.x), r1 = bfpair(ur.y), r2 = bfpair(ur.z), r3 = bfpair(ur.w);

  const unsigned int cbyte = (unsigned int)(ch0 << 1);
  const char* xb8 = (const char*)xlr;

  f32x2 a0 = {0.f,0.f}, a1 = {0.f,0.f}, a2 = {0.f,0.f}, a3 = {0.f,0.f};
  float l = 0.f;

  auto edgeq = [&](uint4 u, f32x2& x0, f32x2& x1, f32x2& x2, f32x2& x3)->float{
    x0 = bfpair(u.x); x1 = bfpair(u.y); x2 = bfpair(u.z); x3 = bfpair(u.w);
    f32x2 t0 = x0 + r0, t1 = x1 + r1, t2 = x2 + r2, t3 = x3 + r3;
    f32x2 m0 = __builtin_elementwise_max(t0, t0 * SLOPE);
    f32x2 m1 = __builtin_elementwise_max(t1, t1 * SLOPE);
    f32x2 m2 = __builtin_elementwise_max(t2, t2 * SLOPE);
    f32x2 m3 = __builtin_elementwise_max(t3, t3 * SLOPE);
    f32x2 d = m0 * av0 + m1 * av1 + m2 * av2 + m3 * av3;
    float p = dpp_sum4(d.x + d.y);    // head's 32 ch live on one quad
    return hw_exp2(p);
  };

  const int e0 = rp[node], e1 = rp[node + 1];
  int e = e0;
  for (; e + 4 <= e1; e += 4){
    unsigned int o0 = csr[e + pair] | cbyte;
    unsigned int o1 = csr[e + 2 + pair] | cbyte;
    uint4 u0 = *(const uint4*)(xb8 + o0);
    uint4 u1 = *(const uint4*)(xb8 + o1);
    f32x2 x0, x1, x2, x3;
    float q0 = edgeq(u0, x0, x1, x2, x3);
    a0 += q0 * x0; a1 += q0 * x1; a2 += q0 * x2; a3 += q0 * x3;
    float q1 = edgeq(u1, x0, x1, x2, x3);
    a0 += q1 * x0; a1 += q1 * x1; a2 += q1 * x2; a3 += q1 * x3;
    l += q0 + q1;
  }
  for (; e < e1; e += 2){
    int idx = e + pair;
    unsigned int o = csr[(idx < e1) ? idx : (e1 - 1)] | cbyte;
    uint4 u = *(const uint4*)(xb8 + o);
    f32x2 x0, x1, x2, x3;
    float q = edgeq(u, x0, x1, x2, x3);
    q = (idx < e1) ? q : 0.f;
    a0 += q * x0; a1 += q * x1; a2 += q * x2; a3 += q * x3;
    l += q;
  }

  // combine the two edge-stream halves (lane ^ 32)
  l    += __shfl_xor(l, 32);
  a0.x += __shfl_xor(a0.x, 32); a0.y += __shfl_xor(a0.y, 32);
  a1.x += __shfl_xor(a1.x, 32); a1.y += __shfl_xor(a1.y, 32);
  a2.x += __shfl_xor(a2.x, 32); a2.y += __shfl_xor(a2.y, 32);
  a3.x += __shfl_xor(a3.x, 32); a3.y += __shfl_xor(a3.y, 32);

  const float inv = 1.f / l;
  float f[8];
  f[0] = a0.x * inv; f[1] = a0.y * inv;
  f[2] = a1.x * inv; f[3] = a1.y * inv;
  f[4] = a2.x * inv; f[5] = a2.y * inv;
  f[6] = a3.x * inv; f[7] = a3.y * inv;
  {
    float4 g_lo = *(const float4*)(gb + ch0);
    float4 g_hi = *(const float4*)(gb + ch0 + 4);
    f[0] += g_lo.x; f[1] += g_lo.y; f[2] += g_lo.z; f[3] += g_lo.w;
    f[4] += g_hi.x; f[5] += g_hi.y; f[6] += g_hi.z; f[7] += g_hi.w;
  }
  if (use_res){
    uint4 hv = *(const uint4*)(hold + (size_t)node * HDIM + ch0);
    f32x2 h0 = bfpair(hv.x), h1 = bfpair(hv.y), h2 = bfpair(hv.z), h3 = bfpair(hv.w);
    f[0] += h0.x; f[1] += h0.y; f[2] += h1.x; f[3] += h1.y;
    f[4] += h2.x; f[5] += h2.y; f[6] += h3.x; f[7] += h3.y;
  }
  float s = ((f[0] + f[1]) + (f[2] + f[3])) + ((f[4] + f[5]) + (f[6] + f[7]));
  s = dpp_sum16(s);
  s += __shfl_xor(s, 16);
  const float mean = s * (1.f / HDIM);
  float d2 = 0.f;
  float dd[8];
  #pragma unroll
  for (int j = 0; j < 8; ++j){ dd[j] = f[j] - mean; d2 += dd[j] * dd[j]; }
  d2 = dpp_sum16(d2);
  d2 += __shfl_xor(d2, 16);
  const float rs = rsqrtf(d2 * (1.f / HDIM) + EPSN);
  float4 lg_lo = *(const float4*)(lg + ch0), lg_hi = *(const float4*)(lg + ch0 + 4);
  float4 lb_lo = *(const float4*)(lb + ch0), lb_hi = *(const float4*)(lb + ch0 + 4);
  float og[8] = {lg_lo.x, lg_lo.y, lg_lo.z, lg_lo.w, lg_hi.x, lg_hi.y, lg_hi.z, lg_hi.w};
  float ob[8] = {lb_lo.x, lb_lo.y, lb_lo.z, lb_lo.w, lb_hi.x, lb_hi.y, lb_hi.z, lb_hi.w};
  bf16x8 st;
  #pragma unroll
  for (int j = 0; j < 8; ++j){
    float v = dd[j] * rs * og[j] + ob[j];
    v = v > 0.f ? v : 0.f;
    st[j] = (short)f2bf(v);
  }
  if (pair == 0)
    *(bf16x8*)(hnew + (size_t)node * HDIM + ch0) = st;
}

// ---------------- mean pool: batch sorted -> per-graph segment reduce ----------------
__global__ __launch_bounds__(256) void k_pool2(
    const unsigned short* __restrict__ ho, const int* __restrict__ batch,
    float* __restrict__ gr, int n)
{
  const int g = blockIdx.x;
  int lo = 0, hi = n;
  while (lo < hi){ int mid = (lo + hi) >> 1; if (batch[mid] < g) lo = mid + 1; else hi = mid; }
  const int s = lo;
  hi = n;
  while (lo < hi){ int mid = (lo + hi) >> 1; if (batch[mid] < g + 1) lo = mid + 1; else hi = mid; }
  const int e = lo;
  const int j = threadIdx.x;
  float acc = 0.f;
  for (int i = s; i < e; ++i) acc += bf2f(ho[(size_t)i * HDIM + j]);
  int c = e - s; if (c < 1) c = 1;
  gr[(size_t)g * HDIM + j] = acc / (float)c;
}

// ---------------- tiny MLP ----------------
__global__ void k_fc(const float* __restrict__ in, const float* __restrict__ w,
                     const float* __restrict__ b, float* __restrict__ out,
                     int kin, int kout){
  __shared__ float s[256];
  int g = blockIdx.x, j = threadIdx.x;
  for (int k = j; k < kin; k += blockDim.x) s[k] = in[(size_t)g * kin + k];
  __syncthreads();
  float a = b[j];
  for (int k = 0; k < kin; ++k) a = fmaf(s[k], w[k * kout + j], a);
  out[(size_t)g * kout + j] = a;
}

// fused BN stats + apply + relu: one block per channel
__global__ __launch_bounds__(256) void k_bn(float* __restrict__ z,
    const float* __restrict__ gam, const float* __restrict__ bet, int g_, int c_){
  const int c = blockIdx.x;
  float s = 0.f, s2 = 0.f;
  for (int r = threadIdx.x; r < g_; r += 256){
    float v = z[(size_t)r * c_ + c];
    s += v; s2 += v * v;
  }
  #pragma unroll
  for (int off = 1; off < 64; off <<= 1){ s += __shfl_xor(s, off); s2 += __shfl_xor(s2, off); }
  __shared__ float sw[4], sw2[4];
  __shared__ float smean, srstd;
  int lane = threadIdx.x & 63, wid = threadIdx.x >> 6;
  if (lane == 0){ sw[wid] = s; sw2[wid] = s2; }
  __syncthreads();
  if (threadIdx.x == 0){
    float ts = sw[0] + sw[1] + sw[2] + sw[3];
    float ts2 = sw2[0] + sw2[1] + sw2[2] + sw2[3];
    float mm = ts / g_;
    float vv = ts2 / g_ - mm * mm;
    smean = mm; srstd = rsqrtf(vv + EPSN);
  }
  __syncthreads();
  const float mm = smean, rs = srstd, gg = gam[c], bb = bet[c];
  for (int r = threadIdx.x; r < g_; r += 256){
    float v = (z[(size_t)r * c_ + c] - mm) * rs * gg + bb;
    z[(size_t)r * c_ + c] = v > 0.f ? v : 0.f;
  }
}

__global__ __launch_bounds__(256) void k_out(const float* __restrict__ z,
    const float* __restrict__ w, const float* __restrict__ b,
    float* __restrict__ out, int g_){
  int g = blockIdx.x * 4 + (threadIdx.x >> 6);
  if (g >= g_) return;
  int lane = threadIdx.x & 63;
  float v = z[(size_t)g * 64 + lane] * w[lane];
  #pragma unroll
  for (int off = 1; off < 64; off <<= 1) v += __shfl_xor(v, off);
  if (lane == 0) out[g] = v + b[0];
}

// ---------------- host ----------------
extern "C" void kernel_launch(void* const* d_in, const int* in_sizes, int n_in,
                              void* d_out, int out_size, void* d_ws, size_t ws_size,
                              hipStream_t stream)
{
  const float* x     = (const float*)d_in[0];
  const int*   ei    = (const int*)  d_in[1];
  const int*   batch = (const int*)  d_in[2];
  const float* in_w  = (const float*)d_in[3];
  const float* in_b  = (const float*)d_in[4];
  const float* wl    = (const float*)d_in[5];
  const float* wl_b  = (const float*)d_in[6];
  const float* wr    = (const float*)d_in[7];
  const float* wr_b  = (const float*)d_in[8];
  const float* att   = (const float*)d_in[9];
  const float* gat_b = (const float*)d_in[10];
  const float* ln_g  = (const float*)d_in[11];
  const float* ln_b  = (const float*)d_in[12];
  const float* out_w = (const float*)d_in[13];
  const float* out_b = (const float*)d_in[14];
  const float* p1_w  = (const float*)d_in[15];
  const float* p1_b  = (const float*)d_in[16];
  const float* bn1_g = (const float*)d_in[17];
  const float* bn1_b = (const float*)d_in[18];
  const float* p2_w  = (const float*)d_in[19];
  const float* p2_b  = (const float*)d_in[20];
  const float* bn2_g = (const float*)d_in[21];
  const float* bn2_b = (const float*)d_in[22];
  const float* p3_w  = (const float*)d_in[23];
  const float* p3_b  = (const float*)d_in[24];

  const int n = in_sizes[0] / F_IN;     // 50000
  const int e = in_sizes[1] / 2;        // 800000
  const int g = out_size;               // 500
  const int nb = (n + 255) / 256;

  char* p = (char*)d_ws;
  auto take = [&](size_t bytes)->char*{
    char* q = p; p += ((bytes + 255) & ~(size_t)255); return q;
  };
  unsigned short* hA   = (unsigned short*)take((size_t)n * HDIM * 2);
  unsigned short* hB   = (unsigned short*)take((size_t)n * HDIM * 2);
  unsigned short* xlr  = (unsigned short*)take((size_t)n * 512 * 2);
  unsigned short* WtLR = (unsigned short*)take((size_t)NLAYER * 512 * HDIM * 2);
  unsigned short* WtO  = (unsigned short*)take((size_t)HDIM * HDIM * 2);
  unsigned short* WtI  = (unsigned short*)take((size_t)HDIM * KPAD * 2);
  float* bconc = (float*)take((size_t)NLAYER * 512 * 4);
  int*   deg   = (int*)take((size_t)n * 4);
  int*   rowp  = (int*)take((size_t)(n + 1) * 4);
  int*   cur   = (int*)take((size_t)n * 4);
  unsigned int* csr = (unsigned int*)take((size_t)(e + n) * 4);
  int*   bsum  = (int*)take((size_t)(nb + 1) * 4);
  int*   boff  = (int*)take((size_t)(nb + 1) * 4);
  float* gr    = (float*)take((size_t)g * HDIM * 4);
  float* z1    = (float*)take((size_t)g * 128 * 4);
  float* z2    = (float*)take((size_t)g * 64 * 4);
  unsigned short* xb = xlr;  // alias: xb only needed before first GEMM writes xlr
  (void)ws_size; (void)n_in;

  // CSR build
  hipMemsetAsync(deg, 0, (size_t)n * 4, stream);
  k_hist<<<(e + 255) / 256, 256, 0, stream>>>(ei + e, deg, e);
  k_scan1<<<nb, 256, 0, stream>>>(deg, rowp, bsum, n);
  k_scan2<<<1, 256, 0, stream>>>(bsum, boff, nb);
  k_scan3<<<nb, 256, 0, stream>>>(rowp, cur, boff, n, nb);
  k_fill2<<<(e + n + 255) / 256, 256, 0, stream>>>(ei, ei + e, cur, csr, e, n);

  // fused prep (weights -> frag layout, biases, x)
  const int xconv_blocks = (n * KPAD + 255) / 256;
  k_prep<<<680 + xconv_blocks, 256, 0, stream>>>(
      wl, wr, out_w, in_w, wl_b, wr_b, x, WtLR, WtO, WtI, bconc, xb, n);

  // input projection (MFMA, K=96)
  k_inproj_mfma<<<dim3((n + 127) / 128, 2), 256, 0, stream>>>(xb, WtI, in_b, hA, n);

  unsigned short* hcur = hA;
  unsigned short* hnext = hB;
  for (int i = 0; i < NLAYER; ++i){
    k_gemm_mfma<<<dim3((n + 127) / 128, 4), 256, 0, stream>>>(
        hcur, WtLR + (size_t)i * 512 * HDIM, bconc + i * 512, xlr, n, 512);
    k_gat<<<(n + 3) / 4, 256, 0, stream>>>(xlr, rowp, csr,
        att + (size_t)i * NHEAD * HEADD, gat_b + i * HDIM,
        ln_g + i * HDIM, ln_b + i * HDIM, hcur, hnext, n, i > 0 ? 1 : 0);
    unsigned short* t = hcur; hcur = hnext; hnext = t;
  }
  // output projection
  k_gemm_mfma<<<dim3((n + 127) / 128, 2), 256, 0, stream>>>(
      hcur, WtO, out_b, hnext, n, HDIM);

  // pooling
  k_pool2<<<g, 256, 0, stream>>>(hnext, batch, gr, n);

  // MLP head
  k_fc<<<g, 128, 0, stream>>>(gr, p1_w, p1_b, z1, HDIM, 128);
  k_bn<<<128, 256, 0, stream>>>(z1, bn1_g, bn1_b, g, 128);
  k_fc<<<g, 64, 0, stream>>>(z1, p2_w, p2_b, z2, 128, 64);
  k_bn<<<64, 256, 0, stream>>>(z2, bn2_g, bn2_b, g, 64);
  k_out<<<(g + 3) / 4, 256, 0, stream>>>(z2, p3_w, p3_b, (float*)d_out, g);
}